// Round 1
// baseline (1844.328 us; speedup 1.0000x reference)
//
#include <hip/hip_runtime.h>
#include <hip/hip_bf16.h>

// ---------------------------------------------------------------------------
// NuGraphCore: 10 chained NuGraphBlocks.
// Block = sigmoid edge attention -> featurewise softmax aggregation -> MLP.
//
// Round-3: runtime input-dtype detection (bf16 vs fp32). A probe kernel
// scans x_hit for bf16-Inf/NaN bit patterns at even ushort indices: fp32
// data produces ~0.8% hits (uniform low mantissa bits), bf16 normal data
// produces none. Every input load branches (wave-uniform) on the flag.
// Suspected round-1/2 NaN source: casting fp32 inputs to bf16.
// ---------------------------------------------------------------------------

typedef __bf16 bf16x8 __attribute__((ext_vector_type(8)));
typedef float  f32x4  __attribute__((ext_vector_type(4)));

__device__ __forceinline__ float b2f(ushort u) {
    return (float)__builtin_bit_cast(__bf16, u);
}
__device__ __forceinline__ ushort f2b(float f) {
    __bf16 h = (__bf16)f;
    return __builtin_bit_cast(ushort, h);
}
__device__ __forceinline__ __bf16 bhi(float x) { return (__bf16)x; }
__device__ __forceinline__ __bf16 blo(float x) {
    __bf16 h = (__bf16)x;
    return (__bf16)(x - (float)h);
}

// Dual-dtype loads: isb==1 -> bf16 (ushort), else fp32.
__device__ __forceinline__ float ldx(const void* p, long i, int isb) {
    return isb ? b2f(((const ushort*)p)[i]) : ((const float*)p)[i];
}
__device__ __forceinline__ f32x4 ldx4(const void* p, long i, int isb) {
    f32x4 r;
    if (isb) {
        uint2 v = *(const uint2*)((const ushort*)p + i);   // 8 B, aligned (i%4==0)
        r[0] = b2f((ushort)(v.x & 0xffff));
        r[1] = b2f((ushort)(v.x >> 16));
        r[2] = b2f((ushort)(v.y & 0xffff));
        r[3] = b2f((ushort)(v.y >> 16));
    } else {
        r = *(const f32x4*)((const float*)p + i);
    }
    return r;
}

__device__ __forceinline__ float mishf(float x) {
    // x * tanh(softplus(x)); overflow-safe: exp->inf => log1p->inf => tanh->1
    float sp = log1pf(expf(x));
    return x * tanhf(sp);
}

// ---------------------------------------------------------------------------
// Dtype probe: even-index ushorts of an fp32 buffer are uniform mantissa bits
// (~0.8% decode as bf16 inf/nan); bf16 normal data has zero such patterns.
// flag[0] = 1 -> inputs are bf16; 0 -> fp32.
// ---------------------------------------------------------------------------
__global__ __launch_bounds__(256) void detect_kernel(const ushort* __restrict__ u,
                                                     int* __restrict__ flag)
{
    __shared__ int s_cnt;
    if (threadIdx.x == 0) s_cnt = 0;
    __syncthreads();
    int cnt = 0;
    for (int i = threadIdx.x; i < 8192; i += 256) {
        ushort v = u[2 * i];
        if ((v & 0x7F80u) == 0x7F80u) cnt++;
    }
#pragma unroll
    for (int off = 32; off; off >>= 1) cnt += __shfl_xor(cnt, off, 64);
    if ((threadIdx.x & 63) == 0) atomicAdd(&s_cnt, cnt);
    __syncthreads();
    if (threadIdx.x == 0) flag[0] = (s_cnt == 0) ? 1 : 0;
}

// ---------------------------------------------------------------------------
// Edge pass: one wave per edge, targets restricted to [lo,hi).
//   w  = sigmoid([x_tgt[d], x_src[s]] . edge_w + edge_b)
//   m  = w * x_src[s]
//   den[d-lo][f] += exp(m); num[d-lo][f] += exp(m)*m    (fp32 atomics)
// Modes: 0=fp32, 1=bf16, 2=resolve via flag (original inputs).
// ---------------------------------------------------------------------------
__global__ __launch_bounds__(256) void edge_kernel(
    const void* xsrc, long sOff, int smode,
    const void* xtgt, long tOff, int tmode,
    const int* __restrict__ eidx, int E,
    const void* ew, long ewOff, const void* eb, long ebOff,
    float* __restrict__ den, float* __restrict__ num,
    int lo, int hi, const int* __restrict__ flagp)
{
    int isb = flagp[0];
    int sm = (smode == 2) ? isb : smode;
    int tm = (tmode == 2) ? isb : tmode;

    int lane = threadIdx.x & 63;
    int e = blockIdx.x * 4 + (threadIdx.x >> 6);
    if (e >= E) return;                       // wave-uniform
    int d = eidx[E + e];
    if (d < lo || d >= hi) return;            // wave-uniform chunk filter
    int s = eidx[e];

    float xj = ldx(xsrc, sOff + (long)s * 64 + lane, sm);
    float xi = ldx(xtgt, tOff + (long)d * 64 + lane, tm);
    // cat = [x_i, x_j]: first 64 weights multiply x_i (target)
    float part = xi * ldx(ew, ewOff + lane, isb) + xj * ldx(ew, ewOff + 64 + lane, isb);
#pragma unroll
    for (int off = 32; off; off >>= 1) part += __shfl_xor(part, off, 64);
    float t = part + ldx(eb, ebOff, isb);
    float w = 1.0f / (1.0f + expf(-t));
    float m = w * xj;
    float ex = expf(m);
    long idx = (long)(d - lo) * 64 + lane;
    unsafeAtomicAdd(&den[idx], ex);
    unsafeAtomicAdd(&num[idx], ex * m);
}

// ---------------------------------------------------------------------------
// MLP pass over target range [lo,hi):
//   aggr = num/(den+1e-16); h = mish([aggr, x_tgt] @ W1 + b1)
//   out  = mish(h @ W2 + b2)  (+ optional accumulate for HeteroConv sum)
// One wave per 16-node tile; MFMA 16x16x32 bf16, hi/lo-split A (~fp32 acc).
// ---------------------------------------------------------------------------
__global__ __launch_bounds__(256) void mlp_kernel(
    const float* __restrict__ den, const float* __restrict__ num,
    const void* xt, long xtOff, int tmode,
    const void* w1, long w1Off, const void* b1, long b1Off,
    const void* w2, long w2Off, const void* b2, long b2Off,
    float* outf, void* outd, long outOff,
    int lo, int hi, int accumulate, const int* __restrict__ flagp)
{
    __shared__ __align__(16) ushort W1t[64][144];   // [n][k], 16B-aligned rows
    __shared__ __align__(16) ushort W2t[64][80];
    __shared__ __align__(16) float  A2s[4][16][68]; // per-wave L1->L2 staging

    int isb = flagp[0];
    int tm = (tmode == 2) ? isb : tmode;
    ushort* ob16 = nullptr;
    float*  ob32 = nullptr;
    if (outd) {
        if (isb) ob16 = (ushort*)outd + outOff;
        else     ob32 = (float*)outd + outOff;
    }

    // Stage weights transposed: W1 global is [k=128][n=64]; W1t[n][k] (bf16).
    for (int idx = threadIdx.x; idx < 128 * 64; idx += 256) {
        int k = idx >> 6, n = idx & 63;
        W1t[n][k] = f2b(ldx(w1, w1Off + idx, isb));
    }
    for (int idx = threadIdx.x; idx < 64 * 64; idx += 256) {
        int k = idx >> 6, n = idx & 63;
        W2t[n][k] = f2b(ldx(w2, w2Off + idx, isb));
    }
    __syncthreads();

    int wid = threadIdx.x >> 6, lane = threadIdx.x & 63;
    int m16 = lane & 15, quad = lane >> 4;
    int ntiles = (hi - lo + 15) >> 4;

    for (int tile = blockIdx.x * 4 + wid; tile < ntiles; tile += gridDim.x * 4) {
        int base = lo + (tile << 4);
        int nodeA = base + m16;
        if (nodeA > hi - 1) nodeA = hi - 1;   // tail clamp (rows discarded)
        long aggoff = (long)(nodeA - lo) * 64;
        long xoff   = (long)nodeA * 64;

        bf16x8 Ahi[4], Alo[4];
        // k 0..63: aggr = num/(den+1e-16)
#pragma unroll
        for (int s2 = 0; s2 < 2; ++s2) {
            int k0 = s2 * 32 + quad * 8;
            f32x4 n0v = *(const f32x4*)(num + aggoff + k0);
            f32x4 n1v = *(const f32x4*)(num + aggoff + k0 + 4);
            f32x4 d0v = *(const f32x4*)(den + aggoff + k0);
            f32x4 d1v = *(const f32x4*)(den + aggoff + k0 + 4);
#pragma unroll
            for (int j = 0; j < 4; ++j) {
                float a0 = n0v[j] / (d0v[j] + 1e-16f);
                float a1 = n1v[j] / (d1v[j] + 1e-16f);
                Ahi[s2][j]     = bhi(a0);
                Alo[s2][j]     = blo(a0);
                Ahi[s2][j + 4] = bhi(a1);
                Alo[s2][j + 4] = blo(a1);
            }
        }
        // k 64..127: x_tgt (dtype per tm; bf16 case -> lo parts become 0)
#pragma unroll
        for (int s2 = 2; s2 < 4; ++s2) {
            int k0 = (s2 - 2) * 32 + quad * 8;
            f32x4 x0 = ldx4(xt, xtOff + xoff + k0, tm);
            f32x4 x1 = ldx4(xt, xtOff + xoff + k0 + 4, tm);
#pragma unroll
            for (int j = 0; j < 4; ++j) {
                Ahi[s2][j]     = bhi(x0[j]);
                Alo[s2][j]     = blo(x0[j]);
                Ahi[s2][j + 4] = bhi(x1[j]);
                Alo[s2][j + 4] = blo(x1[j]);
            }
        }

        // Layer 1: C[16 nodes][64] = A[16][128] @ W1[128][64]
        f32x4 acc[4] = {};
#pragma unroll
        for (int t = 0; t < 4; ++t) {
#pragma unroll
            for (int s = 0; s < 4; ++s) {
                bf16x8 B = __builtin_bit_cast(bf16x8,
                    *(const int4*)&W1t[t * 16 + m16][s * 32 + quad * 8]);
                acc[t] = __builtin_amdgcn_mfma_f32_16x16x32_bf16(Ahi[s], B, acc[t], 0, 0, 0);
                acc[t] = __builtin_amdgcn_mfma_f32_16x16x32_bf16(Alo[s], B, acc[t], 0, 0, 0);
            }
        }
        // Epilogue L1: bias + mish -> LDS (C/D layout -> A layout transform)
#pragma unroll
        for (int t = 0; t < 4; ++t) {
            float bias = ldx(b1, b1Off + t * 16 + m16, isb);
#pragma unroll
            for (int r = 0; r < 4; ++r) {
                float x = acc[t][r] + bias;
                A2s[wid][quad * 4 + r][t * 16 + m16] = mishf(x);
            }
        }
        // Cross-lane RAW through LDS within the wave: drain DS queue.
        asm volatile("s_waitcnt lgkmcnt(0)" ::: "memory");

        bf16x8 A2hi[2], A2lo[2];
#pragma unroll
        for (int s2 = 0; s2 < 2; ++s2) {
            int k0 = s2 * 32 + quad * 8;
            f32x4 h0 = *(const f32x4*)&A2s[wid][m16][k0];
            f32x4 h1 = *(const f32x4*)&A2s[wid][m16][k0 + 4];
#pragma unroll
            for (int j = 0; j < 4; ++j) {
                A2hi[s2][j]     = bhi(h0[j]);
                A2lo[s2][j]     = blo(h0[j]);
                A2hi[s2][j + 4] = bhi(h1[j]);
                A2lo[s2][j + 4] = blo(h1[j]);
            }
        }
        // Layer 2
        f32x4 acc2[4] = {};
#pragma unroll
        for (int t = 0; t < 4; ++t) {
#pragma unroll
            for (int s = 0; s < 2; ++s) {
                bf16x8 B = __builtin_bit_cast(bf16x8,
                    *(const int4*)&W2t[t * 16 + m16][s * 32 + quad * 8]);
                acc2[t] = __builtin_amdgcn_mfma_f32_16x16x32_bf16(A2hi[s], B, acc2[t], 0, 0, 0);
                acc2[t] = __builtin_amdgcn_mfma_f32_16x16x32_bf16(A2lo[s], B, acc2[t], 0, 0, 0);
            }
        }
        // Epilogue L2: bias + mish -> outputs
#pragma unroll
        for (int t = 0; t < 4; ++t) {
            float bias = ldx(b2, b2Off + t * 16 + m16, isb);
#pragma unroll
            for (int r = 0; r < 4; ++r) {
                int node = base + quad * 4 + r;
                if (node < hi) {
                    long idx = (long)node * 64 + t * 16 + m16;
                    float y = mishf(acc2[t][r] + bias);
                    if (accumulate)
                        y += outf ? outf[idx] : (ob16 ? b2f(ob16[idx]) : ob32[idx]);
                    if (outf) outf[idx] = y;
                    if (ob16) ob16[idx] = f2b(y);
                    else if (ob32) ob32[idx] = y;
                }
            }
        }
    }
}

// ---------------------------------------------------------------------------
struct HBuf { const void* base; long off; int mode; };   // mode: 0 f32, 1 bf16, 2 flag

static void run_block(HBuf src, HBuf tgt, const int* e, int E, int n_tgt, int bi,
                      const void* edge_w, const void* edge_b,
                      const void* w1, const void* b1,
                      const void* w2, const void* b2,
                      float* den, float* num, int chunkCap,
                      float* outf, void* outd, long outOff, int accumulate,
                      const int* flagp, hipStream_t stream)
{
    for (int lo = 0; lo < n_tgt; lo += chunkCap) {
        int hi = lo + chunkCap < n_tgt ? lo + chunkCap : n_tgt;
        size_t bytes = (size_t)(hi - lo) * 64 * 4;
        (void)hipMemsetAsync(den, 0, bytes, stream);
        (void)hipMemsetAsync(num, 0, bytes, stream);
        int eblocks = (E + 3) / 4;
        edge_kernel<<<eblocks, 256, 0, stream>>>(
            src.base, src.off, src.mode, tgt.base, tgt.off, tgt.mode,
            e, E, edge_w, (long)bi * 128, edge_b, (long)bi,
            den, num, lo, hi, flagp);
        int ntiles = (hi - lo + 15) / 16;
        int mblocks = (ntiles + 3) / 4;
        if (mblocks > 2048) mblocks = 2048;
        mlp_kernel<<<mblocks, 256, 0, stream>>>(
            den, num, tgt.base, tgt.off, tgt.mode,
            w1, (long)bi * 128 * 64, b1, (long)bi * 64,
            w2, (long)bi * 64 * 64, b2, (long)bi * 64,
            outf, outd, outOff, lo, hi, accumulate, flagp);
    }
}

extern "C" void kernel_launch(void* const* d_in, const int* in_sizes, int n_in,
                              void* d_out, int out_size, void* d_ws, size_t ws_size,
                              hipStream_t stream)
{
    (void)in_sizes; (void)n_in; (void)out_size;

    const void* x_hit = d_in[0];    // 300000 x 64
    const void* x_sp  = d_in[1];    //  50000 x 64
    const void* x_oph = d_in[2];    // 200000 x 64
    const void* x_pmt = d_in[3];    //  30000 x 64
    const void* x_opf = d_in[4];    //   2000 x 64
    const void* x_evt = d_in[5];    //    256 x 64
    const void* edge_w = d_in[6];   // [10][128]
    const void* edge_b = d_in[7];   // [10]
    const void* w1 = d_in[8];       // [10][128][64]
    const void* b1 = d_in[9];       // [10][64]
    const void* w2 = d_in[10];      // [10][64][64]
    const void* b2 = d_in[11];      // [10][64]
    const int* e_hit_sp  = (const int*)d_in[12];
    const int* e_oph_pmt = (const int*)d_in[13];
    const int* e_pmt_opf = (const int*)d_in[14];
    const int* e_sp_evt  = (const int*)d_in[15];
    const int* e_opf_evt = (const int*)d_in[16];
    const int* e_evt_sp  = (const int*)d_in[17];
    const int* e_sp_hit  = (const int*)d_in[18];
    const int* e_evt_opf = (const int*)d_in[19];
    const int* e_opf_pmt = (const int*)d_in[20];
    const int* e_pmt_oph = (const int*)d_in[21];

    // Output slot element offsets (dtype-independent).
    const long off_p = 0, off_n = 19200000, off_oph = 22400000,
               off_pmt = 35200000, off_opf = 37120000, off_i = 37248000;

    // Reserve d_ws tail for the dtype flag.
    char* wsc = (char*)d_ws;
    int* flagp = (int*)(wsc + ((ws_size - 64) & ~(size_t)15));
    size_t usable = ws_size > 256 ? ws_size - 256 : 0;
    float* wsf = (float*)d_ws;

    detect_kernel<<<1, 256, 0, stream>>>((const ushort*)x_hit, flagp);

    const size_t nodeFloats = 3200000ull * 2 + 1920000ull * 2 + 128000ull * 2 + 16384ull;
    const size_t nodeBytes  = nodeFloats * 4;
    bool fp32path = usable >= nodeBytes + (8ull << 20);
    size_t capBytes = fp32path ? (usable - nodeBytes) : usable;
    long cap = (long)(capBytes / 512);
    if (cap > 300000) cap = 300000;
    cap &= ~15L;
    if (cap < 16) cap = 16;
    int chunkCap = (int)cap;

    float* den = fp32path ? (wsf + nodeFloats) : wsf;
    float* num = den + (size_t)chunkCap * 64;

    HBuf bhit{x_hit, 0, 2}, bsp{x_sp, 0, 2}, boph{x_oph, 0, 2},
         bpmt{x_pmt, 0, 2}, bopf{x_opf, 0, 2}, bevt{x_evt, 0, 2};

#define W edge_w, edge_b, w1, b1, w2, b2, den, num, chunkCap
    if (fp32path) {
        float* n0   = wsf;
        float* n1   = n0 + 3200000;
        float* pmt0 = n1 + 3200000;
        float* pmt1 = pmt0 + 1920000;
        float* opf0 = pmt1 + 1920000;
        float* opf1 = opf0 + 128000;
        float* iA   = opf1 + 128000;
        HBuf bn0{n0, 0, 0}, bn1{n1, 0, 0}, bpmt0{pmt0, 0, 0}, bpmt1{pmt1, 0, 0},
             bopf0{opf0, 0, 0}, bopf1{opf1, 0, 0}, biA{iA, 0, 0};

        run_block(bhit,  bsp,   e_hit_sp,  300000,  50000, 0, W, n0,   nullptr, 0,      0, flagp, stream);
        run_block(boph,  bpmt,  e_oph_pmt, 400000,  30000, 1, W, pmt0, nullptr, 0,      0, flagp, stream);
        run_block(bpmt0, bopf,  e_pmt_opf,  60000,   2000, 2, W, opf0, nullptr, 0,      0, flagp, stream);
        run_block(bn0,   bevt,  e_sp_evt,   50000,    256, 3, W, iA,   d_out, off_i,    0, flagp, stream);
        run_block(bopf0, bevt,  e_opf_evt,   2000,    256, 4, W, iA,   d_out, off_i,    1, flagp, stream);
        run_block(biA,   bn0,   e_evt_sp,   50000,  50000, 5, W, n1,   d_out, off_n,    0, flagp, stream);
        run_block(bn1,   bhit,  e_sp_hit,  300000, 300000, 6, W, nullptr, d_out, off_p, 0, flagp, stream);
        run_block(biA,   bopf0, e_evt_opf,   2000,   2000, 7, W, opf1, d_out, off_opf,  0, flagp, stream);
        run_block(bopf1, bpmt0, e_opf_pmt,  60000,  30000, 8, W, pmt1, d_out, off_pmt,  0, flagp, stream);
        run_block(bpmt1, boph,  e_pmt_oph, 400000, 200000, 9, W, nullptr, d_out, off_oph, 0, flagp, stream);
    } else {
        // Fallback: intermediates live in the d_out slots at the flag dtype.
        HBuf dn{d_out, off_n, 2}, dpmt{d_out, off_pmt, 2}, dopf{d_out, off_opf, 2},
             di{d_out, off_i, 2};

        run_block(bhit, bsp,  e_hit_sp,  300000,  50000, 0, W, nullptr, d_out, off_n,   0, flagp, stream);
        run_block(boph, bpmt, e_oph_pmt, 400000,  30000, 1, W, nullptr, d_out, off_pmt, 0, flagp, stream);
        run_block(dpmt, bopf, e_pmt_opf,  60000,   2000, 2, W, nullptr, d_out, off_opf, 0, flagp, stream);
        run_block(dn,   bevt, e_sp_evt,   50000,    256, 3, W, nullptr, d_out, off_i,   0, flagp, stream);
        run_block(dopf, bevt, e_opf_evt,   2000,    256, 4, W, nullptr, d_out, off_i,   1, flagp, stream);
        run_block(di,   dn,   e_evt_sp,   50000,  50000, 5, W, nullptr, d_out, off_n,   0, flagp, stream);
        run_block(dn,   bhit, e_sp_hit,  300000, 300000, 6, W, nullptr, d_out, off_p,   0, flagp, stream);
        run_block(di,   dopf, e_evt_opf,   2000,   2000, 7, W, nullptr, d_out, off_opf, 0, flagp, stream);
        run_block(dopf, dpmt, e_opf_pmt,  60000,  30000, 8, W, nullptr, d_out, off_pmt, 0, flagp, stream);
        run_block(dpmt, boph, e_pmt_oph, 400000, 200000, 9, W, nullptr, d_out, off_oph, 0, flagp, stream);
    }
#undef W
}

// Round 2
// 1532.560 us; speedup vs baseline: 1.2034x; 1.2034x over previous
//
#include <hip/hip_runtime.h>
#include <hip/hip_bf16.h>

// ---------------------------------------------------------------------------
// NuGraphCore: 10 chained NuGraphBlocks.
// Block = sigmoid edge attention -> featurewise softmax aggregation -> MLP.
//
// Round-4 (this session r1): mlp_kernel was VALU-bound (VALUBusy 77%,
// MfmaUtil 2.6%, HBM 10%). Replaced libm mish (expf+log1pf+tanhf ~30 instr)
// with closed form x*(1 - 2/((1+e^x)^2+1)) using v_exp_f32 + v_rcp_f32
// (~6 instr), and precise fp32 division with v_rcp_f32. Edge kernel:
// grid-stride (<=2048 blocks), loop-invariant weight loads hoisted,
// __expf/rcp for sigmoid. Fused den/num memsets when chunk is full.
// ---------------------------------------------------------------------------

typedef __bf16 bf16x8 __attribute__((ext_vector_type(8)));
typedef float  f32x4  __attribute__((ext_vector_type(4)));

__device__ __forceinline__ float b2f(ushort u) {
    return (float)__builtin_bit_cast(__bf16, u);
}
__device__ __forceinline__ ushort f2b(float f) {
    __bf16 h = (__bf16)f;
    return __builtin_bit_cast(ushort, h);
}
__device__ __forceinline__ __bf16 bhi(float x) { return (__bf16)x; }
__device__ __forceinline__ __bf16 blo(float x) {
    __bf16 h = (__bf16)x;
    return (__bf16)(x - (float)h);
}

// Dual-dtype loads: isb==1 -> bf16 (ushort), else fp32.
__device__ __forceinline__ float ldx(const void* p, long i, int isb) {
    return isb ? b2f(((const ushort*)p)[i]) : ((const float*)p)[i];
}
__device__ __forceinline__ f32x4 ldx4(const void* p, long i, int isb) {
    f32x4 r;
    if (isb) {
        uint2 v = *(const uint2*)((const ushort*)p + i);   // 8 B, aligned (i%4==0)
        r[0] = b2f((ushort)(v.x & 0xffff));
        r[1] = b2f((ushort)(v.x >> 16));
        r[2] = b2f((ushort)(v.y & 0xffff));
        r[3] = b2f((ushort)(v.y >> 16));
    } else {
        r = *(const f32x4*)((const float*)p + i);
    }
    return r;
}

__device__ __forceinline__ float frcp(float x) {
    return __builtin_amdgcn_rcpf(x);      // v_rcp_f32, ~1 ulp
}

__device__ __forceinline__ float mishf(float x) {
    // mish(x) = x * tanh(log1p(e^x)) = x * (1 - 2/((1+e^x)^2 + 1))
    // Limits: e^x->inf => rcp->0 => x*1 = x.  e^x->0 => 1-2/2 = 0 => 0.
    // (1+e^x)^2 overflows to inf for x > ~44, where tanh==1 exactly in f32.
    float t = __expf(x);                  // v_exp_f32 based, inf-safe
    float u = 1.0f + t;
    float r = 1.0f - 2.0f * frcp(u * u + 1.0f);
    return x * r;
}

// ---------------------------------------------------------------------------
// Dtype probe: even-index ushorts of an fp32 buffer are uniform mantissa bits
// (~0.8% decode as bf16 inf/nan); bf16 normal data has zero such patterns.
// flag[0] = 1 -> inputs are bf16; 0 -> fp32.
// ---------------------------------------------------------------------------
__global__ __launch_bounds__(256) void detect_kernel(const ushort* __restrict__ u,
                                                     int* __restrict__ flag)
{
    __shared__ int s_cnt;
    if (threadIdx.x == 0) s_cnt = 0;
    __syncthreads();
    int cnt = 0;
    for (int i = threadIdx.x; i < 8192; i += 256) {
        ushort v = u[2 * i];
        if ((v & 0x7F80u) == 0x7F80u) cnt++;
    }
#pragma unroll
    for (int off = 32; off; off >>= 1) cnt += __shfl_xor(cnt, off, 64);
    if ((threadIdx.x & 63) == 0) atomicAdd(&s_cnt, cnt);
    __syncthreads();
    if (threadIdx.x == 0) flag[0] = (s_cnt == 0) ? 1 : 0;
}

// ---------------------------------------------------------------------------
// Edge pass: one wave per edge iteration, grid-stride; targets in [lo,hi).
//   w  = sigmoid([x_tgt[d], x_src[s]] . edge_w + edge_b)
//   m  = w * x_src[s]
//   den[d-lo][f] += exp(m); num[d-lo][f] += exp(m)*m    (fp32 atomics)
// Modes: 0=fp32, 1=bf16, 2=resolve via flag (original inputs).
// ---------------------------------------------------------------------------
__global__ __launch_bounds__(256) void edge_kernel(
    const void* xsrc, long sOff, int smode,
    const void* xtgt, long tOff, int tmode,
    const int* __restrict__ eidx, int E,
    const void* ew, long ewOff, const void* eb, long ebOff,
    float* __restrict__ den, float* __restrict__ num,
    int lo, int hi, const int* __restrict__ flagp)
{
    int isb = flagp[0];
    int sm = (smode == 2) ? isb : smode;
    int tm = (tmode == 2) ? isb : tmode;

    int lane = threadIdx.x & 63;
    // Loop-invariant attention weights (per-lane) + bias.
    float wI = ldx(ew, ewOff + lane, isb);        // multiplies x_i (target)
    float wJ = ldx(ew, ewOff + 64 + lane, isb);   // multiplies x_j (source)
    float bias = ldx(eb, ebOff, isb);

    int nwaves = gridDim.x * 4;
    for (int e = blockIdx.x * 4 + (threadIdx.x >> 6); e < E; e += nwaves) {
        int d = eidx[E + e];
        if (d < lo || d >= hi) continue;          // wave-uniform chunk filter
        int s = eidx[e];

        float xj = ldx(xsrc, sOff + (long)s * 64 + lane, sm);
        float xi = ldx(xtgt, tOff + (long)d * 64 + lane, tm);
        float part = xi * wI + xj * wJ;
#pragma unroll
        for (int off = 32; off; off >>= 1) part += __shfl_xor(part, off, 64);
        float t = part + bias;
        float w = frcp(1.0f + __expf(-t));        // sigmoid
        float m = w * xj;
        float ex = __expf(m);
        long idx = (long)(d - lo) * 64 + lane;
        unsafeAtomicAdd(&den[idx], ex);
        unsafeAtomicAdd(&num[idx], ex * m);
    }
}

// ---------------------------------------------------------------------------
// MLP pass over target range [lo,hi):
//   aggr = num/(den+1e-16); h = mish([aggr, x_tgt] @ W1 + b1)
//   out  = mish(h @ W2 + b2)  (+ optional accumulate for HeteroConv sum)
// One wave per 16-node tile; MFMA 16x16x32 bf16, hi/lo-split A (~fp32 acc).
// ---------------------------------------------------------------------------
__global__ __launch_bounds__(256) void mlp_kernel(
    const float* __restrict__ den, const float* __restrict__ num,
    const void* xt, long xtOff, int tmode,
    const void* w1, long w1Off, const void* b1, long b1Off,
    const void* w2, long w2Off, const void* b2, long b2Off,
    float* outf, void* outd, long outOff,
    int lo, int hi, int accumulate, const int* __restrict__ flagp)
{
    __shared__ __align__(16) ushort W1t[64][144];   // [n][k], 16B-aligned rows
    __shared__ __align__(16) ushort W2t[64][80];
    __shared__ __align__(16) float  A2s[4][16][68]; // per-wave L1->L2 staging

    int isb = flagp[0];
    int tm = (tmode == 2) ? isb : tmode;
    ushort* ob16 = nullptr;
    float*  ob32 = nullptr;
    if (outd) {
        if (isb) ob16 = (ushort*)outd + outOff;
        else     ob32 = (float*)outd + outOff;
    }

    // Stage weights transposed: W1 global is [k=128][n=64]; W1t[n][k] (bf16).
    for (int idx = threadIdx.x; idx < 128 * 64; idx += 256) {
        int k = idx >> 6, n = idx & 63;
        W1t[n][k] = f2b(ldx(w1, w1Off + idx, isb));
    }
    for (int idx = threadIdx.x; idx < 64 * 64; idx += 256) {
        int k = idx >> 6, n = idx & 63;
        W2t[n][k] = f2b(ldx(w2, w2Off + idx, isb));
    }
    __syncthreads();

    int wid = threadIdx.x >> 6, lane = threadIdx.x & 63;
    int m16 = lane & 15, quad = lane >> 4;
    int ntiles = (hi - lo + 15) >> 4;

    for (int tile = blockIdx.x * 4 + wid; tile < ntiles; tile += gridDim.x * 4) {
        int base = lo + (tile << 4);
        int nodeA = base + m16;
        if (nodeA > hi - 1) nodeA = hi - 1;   // tail clamp (rows discarded)
        long aggoff = (long)(nodeA - lo) * 64;
        long xoff   = (long)nodeA * 64;

        bf16x8 Ahi[4], Alo[4];
        // k 0..63: aggr = num * rcp(den+1e-16)
#pragma unroll
        for (int s2 = 0; s2 < 2; ++s2) {
            int k0 = s2 * 32 + quad * 8;
            f32x4 n0v = *(const f32x4*)(num + aggoff + k0);
            f32x4 n1v = *(const f32x4*)(num + aggoff + k0 + 4);
            f32x4 d0v = *(const f32x4*)(den + aggoff + k0);
            f32x4 d1v = *(const f32x4*)(den + aggoff + k0 + 4);
#pragma unroll
            for (int j = 0; j < 4; ++j) {
                float a0 = n0v[j] * frcp(d0v[j] + 1e-16f);
                float a1 = n1v[j] * frcp(d1v[j] + 1e-16f);
                Ahi[s2][j]     = bhi(a0);
                Alo[s2][j]     = blo(a0);
                Ahi[s2][j + 4] = bhi(a1);
                Alo[s2][j + 4] = blo(a1);
            }
        }
        // k 64..127: x_tgt (dtype per tm; bf16 case -> lo parts become 0)
#pragma unroll
        for (int s2 = 2; s2 < 4; ++s2) {
            int k0 = (s2 - 2) * 32 + quad * 8;
            f32x4 x0 = ldx4(xt, xtOff + xoff + k0, tm);
            f32x4 x1 = ldx4(xt, xtOff + xoff + k0 + 4, tm);
#pragma unroll
            for (int j = 0; j < 4; ++j) {
                Ahi[s2][j]     = bhi(x0[j]);
                Alo[s2][j]     = blo(x0[j]);
                Ahi[s2][j + 4] = bhi(x1[j]);
                Alo[s2][j + 4] = blo(x1[j]);
            }
        }

        // Layer 1: C[16 nodes][64] = A[16][128] @ W1[128][64]
        f32x4 acc[4] = {};
#pragma unroll
        for (int t = 0; t < 4; ++t) {
#pragma unroll
            for (int s = 0; s < 4; ++s) {
                bf16x8 B = __builtin_bit_cast(bf16x8,
                    *(const int4*)&W1t[t * 16 + m16][s * 32 + quad * 8]);
                acc[t] = __builtin_amdgcn_mfma_f32_16x16x32_bf16(Ahi[s], B, acc[t], 0, 0, 0);
                acc[t] = __builtin_amdgcn_mfma_f32_16x16x32_bf16(Alo[s], B, acc[t], 0, 0, 0);
            }
        }
        // Epilogue L1: bias + mish -> LDS (C/D layout -> A layout transform)
#pragma unroll
        for (int t = 0; t < 4; ++t) {
            float bias = ldx(b1, b1Off + t * 16 + m16, isb);
#pragma unroll
            for (int r = 0; r < 4; ++r) {
                float x = acc[t][r] + bias;
                A2s[wid][quad * 4 + r][t * 16 + m16] = mishf(x);
            }
        }
        // Cross-lane RAW through LDS within the wave: drain DS queue.
        asm volatile("s_waitcnt lgkmcnt(0)" ::: "memory");

        bf16x8 A2hi[2], A2lo[2];
#pragma unroll
        for (int s2 = 0; s2 < 2; ++s2) {
            int k0 = s2 * 32 + quad * 8;
            f32x4 h0 = *(const f32x4*)&A2s[wid][m16][k0];
            f32x4 h1 = *(const f32x4*)&A2s[wid][m16][k0 + 4];
#pragma unroll
            for (int j = 0; j < 4; ++j) {
                A2hi[s2][j]     = bhi(h0[j]);
                A2lo[s2][j]     = blo(h0[j]);
                A2hi[s2][j + 4] = bhi(h1[j]);
                A2lo[s2][j + 4] = blo(h1[j]);
            }
        }
        // Layer 2
        f32x4 acc2[4] = {};
#pragma unroll
        for (int t = 0; t < 4; ++t) {
#pragma unroll
            for (int s = 0; s < 2; ++s) {
                bf16x8 B = __builtin_bit_cast(bf16x8,
                    *(const int4*)&W2t[t * 16 + m16][s * 32 + quad * 8]);
                acc2[t] = __builtin_amdgcn_mfma_f32_16x16x32_bf16(A2hi[s], B, acc2[t], 0, 0, 0);
                acc2[t] = __builtin_amdgcn_mfma_f32_16x16x32_bf16(A2lo[s], B, acc2[t], 0, 0, 0);
            }
        }
        // Epilogue L2: bias + mish -> outputs
#pragma unroll
        for (int t = 0; t < 4; ++t) {
            float bias = ldx(b2, b2Off + t * 16 + m16, isb);
#pragma unroll
            for (int r = 0; r < 4; ++r) {
                int node = base + quad * 4 + r;
                if (node < hi) {
                    long idx = (long)node * 64 + t * 16 + m16;
                    float y = mishf(acc2[t][r] + bias);
                    if (accumulate)
                        y += outf ? outf[idx] : (ob16 ? b2f(ob16[idx]) : ob32[idx]);
                    if (outf) outf[idx] = y;
                    if (ob16) ob16[idx] = f2b(y);
                    else if (ob32) ob32[idx] = y;
                }
            }
        }
    }
}

// ---------------------------------------------------------------------------
struct HBuf { const void* base; long off; int mode; };   // mode: 0 f32, 1 bf16, 2 flag

static void run_block(HBuf src, HBuf tgt, const int* e, int E, int n_tgt, int bi,
                      const void* edge_w, const void* edge_b,
                      const void* w1, const void* b1,
                      const void* w2, const void* b2,
                      float* den, float* num, int chunkCap,
                      float* outf, void* outd, long outOff, int accumulate,
                      const int* flagp, hipStream_t stream)
{
    for (int lo = 0; lo < n_tgt; lo += chunkCap) {
        int hi = lo + chunkCap < n_tgt ? lo + chunkCap : n_tgt;
        size_t bytes = (size_t)(hi - lo) * 64 * 4;
        if (hi - lo == chunkCap) {
            (void)hipMemsetAsync(den, 0, 2 * bytes, stream);   // den|num contiguous
        } else {
            (void)hipMemsetAsync(den, 0, bytes, stream);
            (void)hipMemsetAsync(num, 0, bytes, stream);
        }
        int eblocks = (E + 3) / 4;
        if (eblocks > 2048) eblocks = 2048;
        edge_kernel<<<eblocks, 256, 0, stream>>>(
            src.base, src.off, src.mode, tgt.base, tgt.off, tgt.mode,
            e, E, edge_w, (long)bi * 128, edge_b, (long)bi,
            den, num, lo, hi, flagp);
        int ntiles = (hi - lo + 15) / 16;
        int mblocks = (ntiles + 3) / 4;
        if (mblocks > 2048) mblocks = 2048;
        mlp_kernel<<<mblocks, 256, 0, stream>>>(
            den, num, tgt.base, tgt.off, tgt.mode,
            w1, (long)bi * 128 * 64, b1, (long)bi * 64,
            w2, (long)bi * 64 * 64, b2, (long)bi * 64,
            outf, outd, outOff, lo, hi, accumulate, flagp);
    }
}

extern "C" void kernel_launch(void* const* d_in, const int* in_sizes, int n_in,
                              void* d_out, int out_size, void* d_ws, size_t ws_size,
                              hipStream_t stream)
{
    (void)in_sizes; (void)n_in; (void)out_size;

    const void* x_hit = d_in[0];    // 300000 x 64
    const void* x_sp  = d_in[1];    //  50000 x 64
    const void* x_oph = d_in[2];    // 200000 x 64
    const void* x_pmt = d_in[3];    //  30000 x 64
    const void* x_opf = d_in[4];    //   2000 x 64
    const void* x_evt = d_in[5];    //    256 x 64
    const void* edge_w = d_in[6];   // [10][128]
    const void* edge_b = d_in[7];   // [10]
    const void* w1 = d_in[8];       // [10][128][64]
    const void* b1 = d_in[9];       // [10][64]
    const void* w2 = d_in[10];      // [10][64][64]
    const void* b2 = d_in[11];      // [10][64]
    const int* e_hit_sp  = (const int*)d_in[12];
    const int* e_oph_pmt = (const int*)d_in[13];
    const int* e_pmt_opf = (const int*)d_in[14];
    const int* e_sp_evt  = (const int*)d_in[15];
    const int* e_opf_evt = (const int*)d_in[16];
    const int* e_evt_sp  = (const int*)d_in[17];
    const int* e_sp_hit  = (const int*)d_in[18];
    const int* e_evt_opf = (const int*)d_in[19];
    const int* e_opf_pmt = (const int*)d_in[20];
    const int* e_pmt_oph = (const int*)d_in[21];

    // Output slot element offsets (dtype-independent).
    const long off_p = 0, off_n = 19200000, off_oph = 22400000,
               off_pmt = 35200000, off_opf = 37120000, off_i = 37248000;

    // Reserve d_ws tail for the dtype flag.
    char* wsc = (char*)d_ws;
    int* flagp = (int*)(wsc + ((ws_size - 64) & ~(size_t)15));
    size_t usable = ws_size > 256 ? ws_size - 256 : 0;
    float* wsf = (float*)d_ws;

    detect_kernel<<<1, 256, 0, stream>>>((const ushort*)x_hit, flagp);

    const size_t nodeFloats = 3200000ull * 2 + 1920000ull * 2 + 128000ull * 2 + 16384ull;
    const size_t nodeBytes  = nodeFloats * 4;
    bool fp32path = usable >= nodeBytes + (8ull << 20);
    size_t capBytes = fp32path ? (usable - nodeBytes) : usable;
    long cap = (long)(capBytes / 512);
    if (cap > 300000) cap = 300000;
    cap &= ~15L;
    if (cap < 16) cap = 16;
    int chunkCap = (int)cap;

    float* den = fp32path ? (wsf + nodeFloats) : wsf;
    float* num = den + (size_t)chunkCap * 64;

    HBuf bhit{x_hit, 0, 2}, bsp{x_sp, 0, 2}, boph{x_oph, 0, 2},
         bpmt{x_pmt, 0, 2}, bopf{x_opf, 0, 2}, bevt{x_evt, 0, 2};

#define W edge_w, edge_b, w1, b1, w2, b2, den, num, chunkCap
    if (fp32path) {
        float* n0   = wsf;
        float* n1   = n0 + 3200000;
        float* pmt0 = n1 + 3200000;
        float* pmt1 = pmt0 + 1920000;
        float* opf0 = pmt1 + 1920000;
        float* opf1 = opf0 + 128000;
        float* iA   = opf1 + 128000;
        HBuf bn0{n0, 0, 0}, bn1{n1, 0, 0}, bpmt0{pmt0, 0, 0}, bpmt1{pmt1, 0, 0},
             bopf0{opf0, 0, 0}, bopf1{opf1, 0, 0}, biA{iA, 0, 0};

        run_block(bhit,  bsp,   e_hit_sp,  300000,  50000, 0, W, n0,   nullptr, 0,      0, flagp, stream);
        run_block(boph,  bpmt,  e_oph_pmt, 400000,  30000, 1, W, pmt0, nullptr, 0,      0, flagp, stream);
        run_block(bpmt0, bopf,  e_pmt_opf,  60000,   2000, 2, W, opf0, nullptr, 0,      0, flagp, stream);
        run_block(bn0,   bevt,  e_sp_evt,   50000,    256, 3, W, iA,   d_out, off_i,    0, flagp, stream);
        run_block(bopf0, bevt,  e_opf_evt,   2000,    256, 4, W, iA,   d_out, off_i,    1, flagp, stream);
        run_block(biA,   bn0,   e_evt_sp,   50000,  50000, 5, W, n1,   d_out, off_n,    0, flagp, stream);
        run_block(bn1,   bhit,  e_sp_hit,  300000, 300000, 6, W, nullptr, d_out, off_p, 0, flagp, stream);
        run_block(biA,   bopf0, e_evt_opf,   2000,   2000, 7, W, opf1, d_out, off_opf,  0, flagp, stream);
        run_block(bopf1, bpmt0, e_opf_pmt,  60000,  30000, 8, W, pmt1, d_out, off_pmt,  0, flagp, stream);
        run_block(bpmt1, boph,  e_pmt_oph, 400000, 200000, 9, W, nullptr, d_out, off_oph, 0, flagp, stream);
    } else {
        // Fallback: intermediates live in the d_out slots at the flag dtype.
        HBuf dn{d_out, off_n, 2}, dpmt{d_out, off_pmt, 2}, dopf{d_out, off_opf, 2},
             di{d_out, off_i, 2};

        run_block(bhit, bsp,  e_hit_sp,  300000,  50000, 0, W, nullptr, d_out, off_n,   0, flagp, stream);
        run_block(boph, bpmt, e_oph_pmt, 400000,  30000, 1, W, nullptr, d_out, off_pmt, 0, flagp, stream);
        run_block(dpmt, bopf, e_pmt_opf,  60000,   2000, 2, W, nullptr, d_out, off_opf, 0, flagp, stream);
        run_block(dn,   bevt, e_sp_evt,   50000,    256, 3, W, nullptr, d_out, off_i,   0, flagp, stream);
        run_block(dopf, bevt, e_opf_evt,   2000,    256, 4, W, nullptr, d_out, off_i,   1, flagp, stream);
        run_block(di,   dn,   e_evt_sp,   50000,  50000, 5, W, nullptr, d_out, off_n,   0, flagp, stream);
        run_block(dn,   bhit, e_sp_hit,  300000, 300000, 6, W, nullptr, d_out, off_p,   0, flagp, stream);
        run_block(di,   dopf, e_evt_opf,   2000,   2000, 7, W, nullptr, d_out, off_opf, 0, flagp, stream);
        run_block(dopf, dpmt, e_opf_pmt,  60000,  30000, 8, W, nullptr, d_out, off_pmt, 0, flagp, stream);
        run_block(dpmt, boph, e_pmt_oph, 400000, 200000, 9, W, nullptr, d_out, off_oph, 0, flagp, stream);
    }
#undef W
}